// Round 3
// baseline (563.099 us; speedup 1.0000x reference)
//
#include <hip/hip_runtime.h>
#include <hip/hip_bf16.h>
#include <cstddef>

// ---------------- problem constants ----------------
#define NTOK   64
#define CDIM   192
#define ODIM   576
#define HEADS  6
#define NTHR   384     // 6 waves; wave == head
#define SCALE  0.17677669529663687f   // 1/sqrt(32)

#define WQ_ELEMS (ODIM*CDIM)
#define WP_ELEMS (CDIM*CDIM)

// LDS: per-head [Q 4K | K 4K] x6 = 48K (doubles as P per-head 8K, first 24K doubles as AO),
// then V 4K x6 = 24K. Total 72 KiB -> 2 blocks/CU.
#define OFF_V  49152
#define LDS_BYTES 73728

typedef __attribute__((ext_vector_type(8))) short bf16x8;
typedef __attribute__((ext_vector_type(4))) short bf16x4;
typedef __attribute__((ext_vector_type(4))) float f32x4;

static __device__ __forceinline__ unsigned short f2b(float f) {
    __hip_bfloat16 h = __float2bfloat16(f);   // RNE; compiler emits cvt_pk pairs
    return __builtin_bit_cast(unsigned short, h);
}

// 64B-row tiles (Q/K per head): mix row bits 1-2 into 16B-slot bits -> 2-way max
static __device__ __forceinline__ char* swz64(char* base, int row, int b) {
    return base + row * 64 + (b ^ (((row >> 1) & 3) << 4));
}
// 128B-row tiles (V, P): classic (row&7)<<4 XOR
static __device__ __forceinline__ char* swz128(char* base, int row, int b) {
    return base + ((row * 128 + b) ^ ((row & 7) << 4));
}
// 384B-row tile (AO)
static __device__ __forceinline__ char* swz384(char* base, int row, int b) {
    return base + ((row * 384 + b) ^ ((row & 7) << 4));
}

// ---------------- prep: fp32 weights -> bf16 (scale folded into W_q) ----------------
__global__ __launch_bounds__(256)
void prep_weights(const float* __restrict__ qkv_w, const float* __restrict__ proj_w,
                  unsigned short* __restrict__ wq, unsigned short* __restrict__ wp)
{
    int i = blockIdx.x * 256 + threadIdx.x;
    if (i < WQ_ELEMS) {
        float v = qkv_w[i];
        if (i < CDIM * CDIM) v *= SCALE;
        wq[i] = f2b(v);
    }
    if (i < WP_ELEMS) wp[i] = f2b(proj_w[i]);
}

// ---------------- fused window-attention, per-head wave ownership ----------------
__global__ __launch_bounds__(NTHR, 3)
void win_attn_mfma(const float* __restrict__ x,
                   const float* __restrict__ mask,
                   const unsigned short* __restrict__ wq,
                   const float* __restrict__ qkv_b,
                   const unsigned short* __restrict__ wp,
                   const float* __restrict__ proj_b,
                   const float* __restrict__ bias_table,
                   float* __restrict__ out)
{
    extern __shared__ char smem[];
    const int t  = threadIdx.x;
    const int w  = blockIdx.x;
    const int h  = t >> 6;        // wave == head
    const int l  = t & 63;
    const int lo = l & 15;
    const int hi = l >> 4;

    char* Qh = smem + h * 8192;       // [64 n][32 o'] bf16, 64B rows
    char* Kh = Qh + 4096;
    char* Ph = Qh;                    // [64 n][64 m] bf16, overlays Q+K after QK^T
    char* Vh = smem + OFF_V + h * 4096;  // Vt [32 d'][64 n] bf16, 128B rows
    char* AO = smem;                  // [64 n][192 o] bf16, overlays heads 0-2 region

    const float* xw = x + (size_t)w * (NTOK * CDIM);

    // ---- phase 1: this wave computes q,k,v of head h over all 64 tokens ----
    // q/k tiles use swapped operands (D[o][n]) for packed b64 stores;
    // v uses normal orientation (D[n][o]) for packed b64 stores into Vt.
    const int tq = 2 * h, tk = 12 + 2 * h, tv = 24 + 2 * h;
    f32x4 aq[2][4] = {}, ak[2][4] = {}, av[4][2] = {};

    for (int ks = 0; ks < 6; ++ks) {
        bf16x8 xf[4];
        #pragma unroll
        for (int nt = 0; nt < 4; ++nt) {
            const float* p = xw + (nt * 16 + lo) * CDIM + ks * 32 + hi * 8;
            float4 v0 = *(const float4*)p;
            float4 v1 = *(const float4*)(p + 4);
            bf16x8 pk;
            pk[0] = (short)f2b(v0.x); pk[1] = (short)f2b(v0.y);
            pk[2] = (short)f2b(v0.z); pk[3] = (short)f2b(v0.w);
            pk[4] = (short)f2b(v1.x); pk[5] = (short)f2b(v1.y);
            pk[6] = (short)f2b(v1.z); pk[7] = (short)f2b(v1.w);
            xf[nt] = pk;
        }
        bf16x8 wqf[2], wkf[2], wvf[2];
        #pragma unroll
        for (int j = 0; j < 2; ++j) {
            wqf[j] = *(const bf16x8*)(const void*)(wq + ((tq + j) * 16 + lo) * CDIM + ks * 32 + hi * 8);
            wkf[j] = *(const bf16x8*)(const void*)(wq + ((tk + j) * 16 + lo) * CDIM + ks * 32 + hi * 8);
            wvf[j] = *(const bf16x8*)(const void*)(wq + ((tv + j) * 16 + lo) * CDIM + ks * 32 + hi * 8);
        }
        #pragma unroll
        for (int j = 0; j < 2; ++j)
            #pragma unroll
            for (int nt = 0; nt < 4; ++nt) {
                aq[j][nt] = __builtin_amdgcn_mfma_f32_16x16x32_bf16(wqf[j], xf[nt], aq[j][nt], 0, 0, 0);
                ak[j][nt] = __builtin_amdgcn_mfma_f32_16x16x32_bf16(wkf[j], xf[nt], ak[j][nt], 0, 0, 0);
                av[nt][j] = __builtin_amdgcn_mfma_f32_16x16x32_bf16(xf[nt], wvf[j], av[nt][j], 0, 0, 0);
            }
    }

    // epilogue: +bias, packed b64 LDS stores (wave-private regions, no barrier)
    #pragma unroll
    for (int j = 0; j < 2; ++j) {
        float4 bq = *(const float4*)(qkv_b + (tq + j) * 16 + hi * 4);
        float4 bk = *(const float4*)(qkv_b + (tk + j) * 16 + hi * 4);
        float bqs[4] = {bq.x * SCALE, bq.y * SCALE, bq.z * SCALE, bq.w * SCALE};
        float bks[4] = {bk.x, bk.y, bk.z, bk.w};
        #pragma unroll
        for (int nt = 0; nt < 4; ++nt) {
            int n = nt * 16 + lo;
            bf16x4 pq, pk2;
            #pragma unroll
            for (int r = 0; r < 4; ++r) {
                pq[r]  = (short)f2b(aq[j][nt][r] + bqs[r]);
                pk2[r] = (short)f2b(ak[j][nt][r] + bks[r]);
            }
            *(bf16x4*)swz64(Qh, n, j * 32 + hi * 8) = pq;
            *(bf16x4*)swz64(Kh, n, j * 32 + hi * 8) = pk2;
        }
    }
    #pragma unroll
    for (int nt = 0; nt < 4; ++nt)
        #pragma unroll
        for (int j = 0; j < 2; ++j) {
            float bv = qkv_b[(tv + j) * 16 + lo];
            bf16x4 pv;
            #pragma unroll
            for (int r = 0; r < 4; ++r) pv[r] = (short)f2b(av[nt][j][r] + bv);
            *(bf16x4*)swz128(Vh, j * 16 + lo, (nt * 16 + hi * 4) * 2) = pv;
        }
    asm volatile("s_waitcnt lgkmcnt(0)" ::: "memory");   // own-wave LDS writes visible

    // ---- phase 2: S = Q.K^T + bias + mask (C-init) ----
    const float* maskW = mask + (size_t)w * (NTOK * NTOK);
    f32x4 cs[4][4];
    #pragma unroll
    for (int mt = 0; mt < 4; ++mt) {
        int m = mt * 16 + lo;
        int i2 = m >> 3, j2 = m & 7;
        #pragma unroll
        for (int nt = 0; nt < 4; ++nt)
            #pragma unroll
            for (int r = 0; r < 4; ++r) {
                int n = nt * 16 + hi * 4 + r;
                int i1 = n >> 3, j1 = n & 7;
                cs[nt][mt][r] = bias_table[((i1 - i2 + 7) * 15 + (j1 - j2 + 7)) * HEADS + h]
                              + maskW[n * 64 + m];
            }
    }
    {
        bf16x8 qa[4], kb[4];
        #pragma unroll
        for (int nt = 0; nt < 4; ++nt) qa[nt] = *(const bf16x8*)swz64(Qh, nt * 16 + lo, hi * 16);
        #pragma unroll
        for (int mt = 0; mt < 4; ++mt) kb[mt] = *(const bf16x8*)swz64(Kh, mt * 16 + lo, hi * 16);
        #pragma unroll
        for (int nt = 0; nt < 4; ++nt)
            #pragma unroll
            for (int mt = 0; mt < 4; ++mt)
                cs[nt][mt] = __builtin_amdgcn_mfma_f32_16x16x32_bf16(qa[nt], kb[mt], cs[nt][mt], 0, 0, 0);
    }

    // ---- softmax (rows n over m); P -> wave-private LDS (overlays Q/K) ----
    float inv[4][4];
    #pragma unroll
    for (int nt = 0; nt < 4; ++nt)
        #pragma unroll
        for (int r = 0; r < 4; ++r) {
            float mx = fmaxf(fmaxf(cs[nt][0][r], cs[nt][1][r]),
                             fmaxf(cs[nt][2][r], cs[nt][3][r]));
            mx = fmaxf(mx, __shfl_xor(mx, 1));
            mx = fmaxf(mx, __shfl_xor(mx, 2));
            mx = fmaxf(mx, __shfl_xor(mx, 4));
            mx = fmaxf(mx, __shfl_xor(mx, 8));
            float s = 0.f;
            #pragma unroll
            for (int mt = 0; mt < 4; ++mt) {
                float e = __expf(cs[nt][mt][r] - mx);
                cs[nt][mt][r] = e;
                s += e;
            }
            s += __shfl_xor(s, 1);
            s += __shfl_xor(s, 2);
            s += __shfl_xor(s, 4);
            s += __shfl_xor(s, 8);
            inv[nt][r] = 1.0f / s;
            int n = nt * 16 + hi * 4 + r;
            #pragma unroll
            for (int mt = 0; mt < 4; ++mt)
                *(unsigned short*)swz128(Ph, n, (mt * 16 + lo) * 2) = f2b(cs[nt][mt][r]);
        }
    asm volatile("s_waitcnt lgkmcnt(0)" ::: "memory");

    // ---- phase 3: O = P.V (wave-private) ----
    f32x4 co[4][2] = {};
    #pragma unroll
    for (int ks = 0; ks < 2; ++ks) {
        bf16x8 pa[4], vb[2];
        #pragma unroll
        for (int nt = 0; nt < 4; ++nt)
            pa[nt] = *(const bf16x8*)swz128(Ph, nt * 16 + lo, (ks * 32 + hi * 8) * 2);
        #pragma unroll
        for (int dt = 0; dt < 2; ++dt)
            vb[dt] = *(const bf16x8*)swz128(Vh, dt * 16 + lo, (ks * 32 + hi * 8) * 2);
        #pragma unroll
        for (int nt = 0; nt < 4; ++nt)
            #pragma unroll
            for (int dt = 0; dt < 2; ++dt)
                co[nt][dt] = __builtin_amdgcn_mfma_f32_16x16x32_bf16(pa[nt], vb[dt], co[nt][dt], 0, 0, 0);
    }
    __syncthreads();   // all P reads done before AO overlays heads 0-2 region

    #pragma unroll
    for (int nt = 0; nt < 4; ++nt)
        #pragma unroll
        for (int dt = 0; dt < 2; ++dt)
            #pragma unroll
            for (int r = 0; r < 4; ++r) {
                int n = nt * 16 + hi * 4 + r;
                int d = dt * 16 + lo;
                *(unsigned short*)swz384(AO, n, (h * 32 + d) * 2) =
                    f2b(co[nt][dt][r] * inv[nt][r]);
            }
    __syncthreads();   // AO complete before proj reads

    // ---- phase 4: out = AO . Wp^T + b ----
    f32x4 ac2[4][2] = {};
    for (int ks = 0; ks < 6; ++ks) {
        bf16x8 aa[4], bb[2];
        #pragma unroll
        for (int nt = 0; nt < 4; ++nt)
            aa[nt] = *(const bf16x8*)swz384(AO, nt * 16 + lo, (ks * 32 + hi * 8) * 2);
        #pragma unroll
        for (int j = 0; j < 2; ++j) {
            int o2 = (h * 2 + j) * 16 + lo;
            bb[j] = *(const bf16x8*)(const void*)(wp + o2 * CDIM + ks * 32 + hi * 8);
        }
        #pragma unroll
        for (int nt = 0; nt < 4; ++nt)
            #pragma unroll
            for (int j = 0; j < 2; ++j)
                ac2[nt][j] = __builtin_amdgcn_mfma_f32_16x16x32_bf16(aa[nt], bb[j], ac2[nt][j], 0, 0, 0);
    }
    float* outW = out + (size_t)w * (NTOK * CDIM);
    #pragma unroll
    for (int j = 0; j < 2; ++j) {
        int o2 = (h * 2 + j) * 16 + lo;
        float pb = proj_b[o2];
        #pragma unroll
        for (int nt = 0; nt < 4; ++nt)
            #pragma unroll
            for (int r = 0; r < 4; ++r) {
                int n = nt * 16 + hi * 4 + r;
                outW[n * CDIM + o2] = ac2[nt][j][r] + pb;
            }
    }
}

extern "C" void kernel_launch(void* const* d_in, const int* in_sizes, int n_in,
                              void* d_out, int out_size, void* d_ws, size_t ws_size,
                              hipStream_t stream) {
    const float* x          = (const float*)d_in[0];
    const float* mask       = (const float*)d_in[1];
    const float* qkv_w      = (const float*)d_in[2];
    const float* qkv_b      = (const float*)d_in[3];
    const float* proj_w     = (const float*)d_in[4];
    const float* proj_b     = (const float*)d_in[5];
    const float* bias_table = (const float*)d_in[6];
    float* out = (float*)d_out;

    unsigned short* wq = (unsigned short*)d_ws;
    unsigned short* wp = wq + WQ_ELEMS;

    const int nW = in_sizes[0] / (NTOK * CDIM);   // 4096

    prep_weights<<<dim3((WQ_ELEMS + 255) / 256), dim3(256), 0, stream>>>(qkv_w, proj_w, wq, wp);

    hipFuncSetAttribute(reinterpret_cast<const void*>(win_attn_mfma),
                        hipFuncAttributeMaxDynamicSharedMemorySize, LDS_BYTES);
    hipLaunchKernelGGL(win_attn_mfma, dim3(nW), dim3(NTHR), LDS_BYTES, stream,
                       x, mask, wq, qkv_b, wp, proj_b, bias_table, out);
}